// Round 1
// baseline (511.846 us; speedup 1.0000x reference)
//
#include <hip/hip_runtime.h>

// CropPrompter: fused resize+crop bilinear sampling, LDS row-staged.
// x: [B=8, C=3, T=16, H=512, W=512] fp32 -> out: [8, 3, 16, 224, 224] fp32
//
// Structure: one block (256 thr) per output row (img, sy). The row depends on
// exactly two source rows (y0, y1) and a contiguous x-span of <=226 floats of
// each. Stage both spans in LDS via coalesced float4 loads (<=116 lanes, 1 load
// each), then each of 224 lanes computes one output pixel from LDS.
// This replaces 2x dwordx2 gather loads per output pixel (38.6M gathers,
// ~4x redundant) with ~2.4M streaming float4 loads.

#define CROP   224
#define HSZ    512
#define NIMG   (8 * 3 * 16)        // 384 independent HxW slices
#define NROWS  (NIMG * CROP)       // 86016 output rows = one block each
#define NXCD   8
#define CHUNK  (NROWS / NXCD)      // 10752 (exact: 86016 % 8 == 0 -> bijective)
#define MAXQ   58                  // max float4 quads staged per source row
#define MAXSPAN (MAXQ * 4)         // 232 floats (scale<=1: span <= 224+2 +align)

__global__ __launch_bounds__(256) void crop_prompter_kernel(
    const float* __restrict__ x,
    const int*   __restrict__ cam_views,
    const float* __restrict__ resize,
    const float* __restrict__ y_off,
    const float* __restrict__ x_off,
    float*       __restrict__ out)
{
    __shared__ float lds[2][MAXSPAN];   // 1856 B: [0]=row y0, [1]=row y1

    // XCD-aware bijective swizzle: consecutive work-ids (consecutive sy of the
    // same image, which SHARE a source row) stay on one XCD's L2.
    const int bid = (int)blockIdx.x;
    const int s   = (bid & (NXCD - 1)) * CHUNK + (bid >> 3);

    const int sy  = s % CROP;
    const int img = s / CROP;          // b*48 + c*16 + t
    const int b   = img / 48;

    // Per-clip learned params (block-uniform -> scalarized).
    const int v = cam_views[b];
    const float r  = floorf(fminf(fmaxf(resize[v], 512.0f), 1024.0f));
    const float yo = floorf(fminf(fmaxf(y_off[v],  0.0f), r - 224.0f));
    const float xo = floorf(fminf(fmaxf(x_off[v],  0.0f), r - 224.0f));
    const float scale = 512.0f / r;    // in [0.5, 1]

    // y coords (block-uniform). srcy in [0, 511.5) -> (int) == floor.
    float srcy = fmaxf((yo + (float)sy + 0.5f) * scale - 0.5f, 0.0f);
    const int   y0  = min((int)srcy, HSZ - 1);
    const int   y1  = min(y0 + 1, HSZ - 1);
    const float wy  = srcy - (float)y0;
    const float wyc = 1.0f - wy;

    // x staging window [xf, xf+4*n4): covers x0c(0) .. x0c(223)+1, float4-aligned.
    // x0c = min(floor(srcx), 510); end4 = ((x0c(223)+2)+3)&~3 <= 512 always.
    const float srcx0 = fmaxf((xo +   0.5f) * scale - 0.5f, 0.0f);
    const float srcxL = fmaxf((xo + 223.5f) * scale - 0.5f, 0.0f);
    const int xf   = min((int)srcx0, HSZ - 2) & ~3;
    const int end4 = (min((int)srcxL, HSZ - 2) + 2 + 3) & ~3;
    const int n4   = (end4 - xf) >> 2;          // quads per row, <= 58

    const float* __restrict__ base = x + (size_t)img * (HSZ * HSZ);

    const int t = (int)threadIdx.x;
    if (t < 2 * n4) {                            // <= 116 lanes load
        const int rowsel = (t >= n4) ? 1 : 0;
        const int qi     = t - (rowsel ? n4 : 0);
        const int yr     = rowsel ? y1 : y0;
        float4 q;
        __builtin_memcpy(&q, base + (size_t)yr * HSZ + xf + 4 * qi, sizeof(float4));
        *reinterpret_cast<float4*>(&lds[rowsel][4 * qi]) = q;  // 16B-aligned
    }
    __syncthreads();

    if (t < CROP) {
        float srcx = fmaxf((xo + (float)t + 0.5f) * scale - 0.5f, 0.0f);
        const int   x0 = min((int)srcx, HSZ - 1);
        const float wx = srcx - (float)x0;
        const int   x0c = min(x0, HSZ - 2);      // pair (x0c, x0c+1) is in-span
        const int   li  = x0c - xf;

        const float t0 = lds[0][li], t1 = lds[0][li + 1];
        const float b0 = lds[1][li], b1 = lds[1][li + 1];

        // At the right clamp edge (x0==511): v00==v01==x[511] == pair's .y.
        const bool  edge = (x0 == HSZ - 1);
        const float v00  = edge ? t1 : t0;
        const float v10  = edge ? b1 : b0;

        // rows = top*(1-wy) + bot*wy; out = rows[x0]*(1-wx) + rows[x1]*wx
        const float left  = v00 * wyc + v10 * wy;
        const float right = t1  * wyc + b1  * wy;
        out[((size_t)img * CROP + sy) * CROP + t] = left * (1.0f - wx) + right * wx;
    }
}

extern "C" void kernel_launch(void* const* d_in, const int* in_sizes, int n_in,
                              void* d_out, int out_size, void* d_ws, size_t ws_size,
                              hipStream_t stream) {
    const float* x         = (const float*)d_in[0];
    const int*   cam_views = (const int*)  d_in[1];
    const float* resize    = (const float*)d_in[2];
    const float* y_off     = (const float*)d_in[3];
    const float* x_off     = (const float*)d_in[4];
    float* out = (float*)d_out;

    crop_prompter_kernel<<<NROWS, 256, 0, stream>>>(
        x, cam_views, resize, y_off, x_off, out);
}

// Round 2
// 482.696 us; speedup vs baseline: 1.0604x; 1.0604x over previous
//
#include <hip/hip_runtime.h>

// CropPrompter: fused resize+crop bilinear, row-band tiled.
// x: [8,3,16,512,512] fp32 -> out: [8,3,16,224,224] fp32
//
// One block per (img, 32-output-row tile): 2688 blocks (vs 86016 last round).
// The tile needs <=33 contiguous source rows x a <=232-float x-span; stage the
// band in LDS (<=31.5 KB), then 224 column-threads each compute their column
// params ONCE and sweep 32 rows. This amortizes the per-block dependent
// param-load chain and all x-coordinate math 32x, and halves staging traffic
// (each staged source row serves ~1 output row instead of half of one).

#define CROP   224
#define HSZ    512
#define NIMG   (8 * 3 * 16)       // 384
#define TILE   32                 // output rows per block
#define NTILES (CROP / TILE)      // 7
#define NBLK   (NIMG * NTILES)    // 2688  (2688 % 8 == 0 -> bijective swizzle)
#define NXCD   8
#define CHUNK  (NBLK / NXCD)      // 336
#define MAXR   34                 // staged rows: <= floor(31*scale)+2 <= 33
#define MAXQ   58                 // float4 quads per staged row
#define SPAN   (MAXQ * 4)         // 232 floats

__global__ __launch_bounds__(256) void crop_prompter_kernel(
    const float* __restrict__ x,
    const int*   __restrict__ cam_views,
    const float* __restrict__ resize,
    const float* __restrict__ y_off,
    const float* __restrict__ x_off,
    float*       __restrict__ out)
{
    __shared__ float lds[MAXR][SPAN];    // 31552 B -> 5 blocks/CU

    // XCD-aware bijective swizzle: consecutive s (tiles of one image, which
    // share source rows at tile seams) stay on one XCD's L2.
    const int bid = (int)blockIdx.x;
    const int s   = (bid & (NXCD - 1)) * CHUNK + (bid >> 3);

    const int tile = s % NTILES;
    const int img  = s / NTILES;         // b*48 + c*16 + t
    const int b    = img / 48;
    const int sy0  = tile * TILE;

    // Per-clip learned params (block-uniform -> scalarized). One chain per
    // 7168 output pixels instead of per 224.
    const int v = cam_views[b];
    const float r  = floorf(fminf(fmaxf(resize[v], 512.0f), 1024.0f));
    const float yo = floorf(fminf(fmaxf(y_off[v],  0.0f), r - 224.0f));
    const float xo = floorf(fminf(fmaxf(x_off[v],  0.0f), r - 224.0f));
    const float scale = 512.0f / r;      // in [0.5, 1]

    // Source row band for output rows [sy0, sy0+TILE). srcy>=0 -> (int)==floor.
    const float srcyA = fmaxf((yo + (float)sy0 + 0.5f) * scale - 0.5f, 0.0f);
    const float srcyB = fmaxf((yo + (float)(sy0 + TILE - 1) + 0.5f) * scale - 0.5f, 0.0f);
    const int ylo = min((int)srcyA, HSZ - 1);
    const int yhi = min(min((int)srcyB, HSZ - 1) + 1, HSZ - 1);
    const int nr  = yhi - ylo + 1;       // <= 33

    // x staging window [xf, xf+4*n4): covers min(x0,510)..+1 for all columns.
    const float srcx0 = fmaxf((xo +   0.5f) * scale - 0.5f, 0.0f);
    const float srcxL = fmaxf((xo + 223.5f) * scale - 0.5f, 0.0f);
    const int xf   = min((int)srcx0, HSZ - 2) & ~3;
    const int end4 = (min((int)srcxL, HSZ - 2) + 2 + 3) & ~3;
    const int n4   = (end4 - xf) >> 2;   // <= 58

    const float* __restrict__ base = x + (size_t)img * (HSZ * HSZ);
    const int t = (int)threadIdx.x;

    // Stage the band: nr*n4 <= 1914 float4 quads, coalesced, ~7.5 per thread.
    const int nq = nr * n4;
    for (int idx = t; idx < nq; idx += 256) {
        const int ri = idx / n4;
        const int qi = idx - ri * n4;
        float4 q;
        __builtin_memcpy(&q, base + (size_t)(ylo + ri) * HSZ + xf + 4 * qi,
                         sizeof(float4));
        *reinterpret_cast<float4*>(&lds[ri][4 * qi]) = q;   // 16B-aligned
    }
    __syncthreads();

    if (t < CROP) {
        // Column params once per thread, reused over TILE rows.
        float srcx = fmaxf((xo + (float)t + 0.5f) * scale - 0.5f, 0.0f);
        const int   x0   = min((int)srcx, HSZ - 1);
        const float wx   = srcx - (float)x0;
        const float wxc  = 1.0f - wx;
        const int   li   = min(x0, HSZ - 2) - xf;   // pair (li, li+1) staged
        const bool  edge = (x0 == HSZ - 1);

        size_t op = ((size_t)img * CROP + sy0) * CROP + t;
#pragma unroll 4
        for (int rr = 0; rr < TILE; ++rr, op += CROP) {
            float srcy = fmaxf((yo + (float)(sy0 + rr) + 0.5f) * scale - 0.5f, 0.0f);
            const int   y0  = min((int)srcy, HSZ - 1);
            const float wy  = srcy - (float)y0;
            const float wyc = 1.0f - wy;
            const int   ry0 = y0 - ylo;
            const int   ry1 = min(y0 + 1, HSZ - 1) - ylo;

            const float t0 = lds[ry0][li], t1 = lds[ry0][li + 1];
            const float b0 = lds[ry1][li], b1 = lds[ry1][li + 1];

            // Right clamp edge: v00==v01==row[511] == pair's high element.
            const float v00 = edge ? t1 : t0;
            const float v10 = edge ? b1 : b0;

            const float left  = v00 * wyc + v10 * wy;
            const float right = t1  * wyc + b1  * wy;
            out[op] = left * wxc + right * wx;
        }
    }
}

extern "C" void kernel_launch(void* const* d_in, const int* in_sizes, int n_in,
                              void* d_out, int out_size, void* d_ws, size_t ws_size,
                              hipStream_t stream) {
    const float* x         = (const float*)d_in[0];
    const int*   cam_views = (const int*)  d_in[1];
    const float* resize    = (const float*)d_in[2];
    const float* y_off     = (const float*)d_in[3];
    const float* x_off     = (const float*)d_in[4];
    float* out = (float*)d_out;

    crop_prompter_kernel<<<NBLK, 256, 0, stream>>>(
        x, cam_views, resize, y_off, x_off, out);
}